// Round 1
// baseline (579.348 us; speedup 1.0000x reference)
//
#include <hip/hip_runtime.h>
#include <math.h>

#define BSZ   4
#define SEQL  2048
#define DIN   40
#define DM    128
#define DI    256
#define DS    16
#define NL    4
#define NHEAD 4
#define DHEAD 32
#define KLM   100
#define NC    128       // chunks per sequence
#define TC    16        // SEQL / NC
#define NROWS 8

__device__ __forceinline__ float sigmoidf_(float x){ return 1.0f/(1.0f + expf(-x)); }
__device__ __forceinline__ float siluf_(float x){ return x/(1.0f + expf(-x)); }
__device__ __forceinline__ float softplusf_(float x){ return fmaxf(x,0.0f) + log1pf(expf(-fabsf(x))); }

__device__ __forceinline__ float block_sum256(float v, float* red){
  #pragma unroll
  for (int o=32;o>0;o>>=1) v += __shfl_down(v,o,64);
  __syncthreads();
  if ((threadIdx.x & 63)==0) red[threadIdx.x>>6] = v;
  __syncthreads();
  return red[0]+red[1]+red[2]+red[3];
}
__device__ __forceinline__ int block_isum256(int v, int* red){
  #pragma unroll
  for (int o=32;o>0;o>>=1) v += __shfl_down(v,o,64);
  __syncthreads();
  if ((threadIdx.x & 63)==0) red[threadIdx.x>>6] = v;
  __syncthreads();
  return red[0]+red[1]+red[2]+red[3];
}
__device__ __forceinline__ void load16(const float* p, float* r){
  const float4* q = (const float4*)p;
  float4 a=q[0], b=q[1], c=q[2], d=q[3];
  r[0]=a.x;r[1]=a.y;r[2]=a.z;r[3]=a.w; r[4]=b.x;r[5]=b.y;r[6]=b.z;r[7]=b.w;
  r[8]=c.x;r[9]=c.y;r[10]=c.z;r[11]=c.w; r[12]=d.x;r[13]=d.y;r[14]=d.z;r[15]=d.w;
}
__device__ __forceinline__ void store16(float* p, const float* r){
  float4* q = (float4*)p;
  q[0]=make_float4(r[0],r[1],r[2],r[3]);  q[1]=make_float4(r[4],r[5],r[6],r[7]);
  q[2]=make_float4(r[8],r[9],r[10],r[11]);q[3]=make_float4(r[12],r[13],r[14],r[15]);
}

// ---------------- embed: h=(x@eW+eb)*w, skip=(x@sW+sb)*w ----------------
__global__ __launch_bounds__(128) void embed_kernel(
    const float* __restrict__ x, const float* __restrict__ hw,
    const float* __restrict__ eW, const float* __restrict__ eb,
    const float* __restrict__ sW, const float* __restrict__ sb,
    float* __restrict__ hb, float* __restrict__ sk)
{
  __shared__ float xr[DIN];
  const size_t R = blockIdx.x;
  const int t = threadIdx.x;
  if (t < DIN) xr[t] = x[R*DIN + t];
  __syncthreads();
  float a = eb[t], s = sb[t];
  #pragma unroll 8
  for (int k=0;k<DIN;k++){
    const float xv = xr[k];
    a = fmaf(xv, eW[(size_t)k*DM + t], a);
    s = fmaf(xv, sW[(size_t)k*DM + t], s);
  }
  const float w = hw[R];
  hb[R*DM + t] = a*w;
  sk[R*DM + t] = s*w;
}

// ---------------- per-layer "pre": LN -> in_proj -> silu -> x_proj -> B/C/dt/lam ----------------
__global__ __launch_bounds__(256) void pre_kernel(
    const float* __restrict__ hb,
    const float* __restrict__ Wi, const float* __restrict__ Wx,
    const float* __restrict__ Wdt, const float* __restrict__ bdt,
    const float* __restrict__ Bb, const float* __restrict__ Cb,
    const float* __restrict__ Bnw, const float* __restrict__ Cnw,
    const float* __restrict__ lnw, const float* __restrict__ lnb,
    float* __restrict__ xpb, float* __restrict__ zsb, float* __restrict__ dtb,
    float* __restrict__ Bmb, float* __restrict__ Cmb,
    float* __restrict__ lamb, float* __restrict__ mdtb)
{
  __shared__ float xin[NROWS][DM];
  __shared__ float xps[NROWS][DI+2];
  __shared__ float spl[NROWS][40];
  __shared__ float red_f[4];

  const int t = threadIdx.x;
  const size_t R0 = (size_t)blockIdx.x * NROWS;

  { // LayerNorm: 32 threads per row (two-pass)
    const int r = t >> 5, j = t & 31;
    const float4 v = ((const float4*)(hb + (R0 + r)*DM))[j];
    float s = v.x+v.y+v.z+v.w;
    #pragma unroll
    for (int o=16;o>0;o>>=1) s += __shfl_xor(s,o,32);
    const float m = s*(1.0f/DM);
    const float dx=v.x-m, dy=v.y-m, dz=v.z-m, dw=v.w-m;
    float ss = dx*dx+dy*dy+dz*dz+dw*dw;
    #pragma unroll
    for (int o=16;o>0;o>>=1) ss += __shfl_xor(ss,o,32);
    const float inv = 1.0f/sqrtf(ss*(1.0f/DM) + 1e-5f);
    const int c = j*4;
    xin[r][c+0] = dx*inv*lnw[c+0] + lnb[c+0];
    xin[r][c+1] = dy*inv*lnw[c+1] + lnb[c+1];
    xin[r][c+2] = dz*inv*lnw[c+2] + lnb[c+2];
    xin[r][c+3] = dw*inv*lnw[c+3] + lnb[c+3];
  }
  __syncthreads();

  { // xz = xin @ Wi (512 cols); thread t owns cols t (->xp) and t+256 (->z)
    float a0[NROWS], a1[NROWS];
    #pragma unroll
    for (int r=0;r<NROWS;r++){ a0[r]=0.0f; a1[r]=0.0f; }
    for (int k=0;k<DM;k++){
      const float w0 = Wi[(size_t)k*(2*DI) + t];
      const float w1 = Wi[(size_t)k*(2*DI) + DI + t];
      #pragma unroll
      for (int r=0;r<NROWS;r++){
        const float xv = xin[r][k];
        a0[r] = fmaf(xv, w0, a0[r]);
        a1[r] = fmaf(xv, w1, a1[r]);
      }
    }
    #pragma unroll
    for (int r=0;r<NROWS;r++){
      const float xpv = siluf_(a0[r]);
      const float zv  = siluf_(a1[r]);
      xps[r][t] = xpv;
      xpb[(R0+r)*DI + t] = xpv;
      zsb[(R0+r)*DI + t] = zv;
    }
  }
  __syncthreads();

  // sp = xp @ Wx (34 outputs per row)
  for (int task=t; task<NROWS*34; task+=256){
    const int r = task/34, o2 = task - r*34;
    float a = 0.0f;
    #pragma unroll 8
    for (int k=0;k<DI;k++) a = fmaf(xps[r][k], Wx[(size_t)k*34 + o2], a);
    spl[r][o2] = a;
  }
  __syncthreads();

  { // B/C rms-norm (pre-rotation). threads 0..127: B, 128..255: C
    const int half = t >> 7;
    const int r = (t >> 4) & 7, s = t & 15;
    const float* bias = half ? Cb : Bb;
    const float* wn   = half ? Cnw : Bnw;
    const float v = spl[r][half*DS + s] + bias[s];
    float ss = v*v;
    #pragma unroll
    for (int o=8;o>0;o>>=1) ss += __shfl_xor(ss,o,16);
    const float inv = 1.0f/sqrtf(ss*(1.0f/DS) + 1.1920929e-07f);
    (half ? Cmb : Bmb)[(R0+r)*DS + s] = v*inv*wn[s];
  }

  // dt = softplus(dt_in*Wdt + bdt); mean_dt; lam = sigmoid(lam_in)
  const float wdt = Wdt[t], bdtv = bdt[t];
  for (int r=0;r<NROWS;r++){
    const float dval = softplusf_(fmaf(spl[r][32], wdt, bdtv));
    dtb[(R0+r)*DI + t] = dval;
    const float s = block_sum256(dval, red_f);
    if (t == 0){
      mdtb[R0+r] = s*(1.0f/DI);
      lamb[R0+r] = sigmoidf_(spl[r][33]);
    }
  }
}

// ---------------- cumsum of mean_dt per batch (double precision) ----------------
__global__ __launch_bounds__(256) void cumsum_kernel(const float* __restrict__ mdt, double* __restrict__ angs){
  __shared__ double part[256];
  const int b = blockIdx.x, t = threadIdx.x;
  const float* p = mdt + (size_t)b*SEQL;
  double vals[8], loc = 0.0;
  #pragma unroll
  for (int q=0;q<8;q++){ vals[q] = (double)p[t*8+q]; loc += vals[q]; }
  part[t] = loc;
  __syncthreads();
  for (int o=1;o<256;o<<=1){
    const double add = (t>=o) ? part[t-o] : 0.0;
    __syncthreads();
    part[t] += add;
    __syncthreads();
  }
  double run = part[t] - loc;   // exclusive prefix of this thread's span
  double* ap = angs + (size_t)b*SEQL + (size_t)t*8;
  #pragma unroll
  for (int q=0;q<8;q++){ run += vals[q]; ap[q] = run; }
}

// ---------------- rope rotation of Bm/Cm in place ----------------
__global__ __launch_bounds__(256) void rot_kernel(
    const double* __restrict__ angs, const float* __restrict__ rf,
    float* __restrict__ Bmb, float* __restrict__ Cmb)
{
  const int id = blockIdx.x*256 + threadIdx.x;   // BSZ*SEQL*8
  const int f = id & 7;
  const size_t R = (size_t)(id >> 3);
  const double xfr = (double)rf[f];
  const double fq = fmax(xfr, 0.0) + log1p(exp(-fabs(xfr)));  // softplus
  const double a = angs[R]*fq;
  const float ca = (float)cos(a), sa = (float)sin(a);
  float e = Bmb[R*DS + 2*f], o = Bmb[R*DS + 2*f + 1];
  Bmb[R*DS + 2*f]     = e*ca - o*sa;
  Bmb[R*DS + 2*f + 1] = e*sa + o*ca;
  e = Cmb[R*DS + 2*f]; o = Cmb[R*DS + 2*f + 1];
  Cmb[R*DS + 2*f]     = e*ca - o*sa;
  Cmb[R*DS + 2*f + 1] = e*sa + o*ca;
}

// ---------------- scan phase 1: per-chunk local scan (h from 0) + decay product ----------------
__global__ __launch_bounds__(256) void scan1_kernel(
    const float* __restrict__ xp, const float* __restrict__ dtb,
    const float* __restrict__ Bmb, const float* __restrict__ lamb,
    const float* __restrict__ Alog, float* __restrict__ hend, float* __restrict__ Pp)
{
  const int id = blockIdx.x*256 + threadIdx.x;   // (b*NC + c)*DI + d
  const int d = id & (DI-1);
  const int c = (id >> 8) & (NC-1);
  const int b = id >> 15;
  float A[DS];
  #pragma unroll
  for (int s=0;s<DS;s++) A[s] = fminf(-expf(Alog[d*DS+s]), -1e-4f);
  const size_t bL = (size_t)b*SEQL;
  const int t0 = c*TC;
  float h[DS], P[DS], Bprev[DS];
  #pragma unroll
  for (int s=0;s<DS;s++){ h[s]=0.0f; P[s]=1.0f; Bprev[s]=0.0f; }
  float xpm1 = 0.0f;
  int tstart = t0;
  if (t0 > 0){
    load16(Bmb + (bL + t0 - 1)*DS, Bprev);
    xpm1 = xp[(bL + t0 - 1)*DI + d];
  } else {
    // t = 0 special: u = dt * Bx
    const size_t rowE = bL*DI + d;
    const float dtv = dtb[rowE];
    const float xpv = xp[rowE];
    float Bcur[DS]; load16(Bmb + bL*DS, Bcur);
    #pragma unroll
    for (int s=0;s<DS;s++){
      const float a = __expf(A[s]*dtv);
      h[s] = dtv*(Bcur[s]*xpv);
      P[s] *= a;
      Bprev[s] = Bcur[s];
    }
    xpm1 = xpv;
    tstart = 1;
  }
  for (int t=tstart; t<t0+TC; ++t){
    const size_t rowE = (bL + t)*DI + d;
    const float dtv = dtb[rowE];
    const float xpv = xp[rowE];
    const float lamv = lamb[bL + t];
    float Bcur[DS]; load16(Bmb + (bL + t)*DS, Bcur);
    const float dl = dtv*lamv;
    const float dml = dtv - dl;
    const float bxp_s = xpm1, bx_s = xpv;
    #pragma unroll
    for (int s=0;s<DS;s++){
      const float a = __expf(A[s]*dtv);
      const float u = fmaf(dml*a, Bprev[s]*bxp_s, dl*(Bcur[s]*bx_s));
      h[s] = fmaf(a, h[s], u);
      P[s] *= a;
      Bprev[s] = Bcur[s];
    }
    xpm1 = xpv;
  }
  store16(hend + (size_t)id*DS, h);
  store16(Pp   + (size_t)id*DS, P);
}

// ---------------- scan phase 2: sequential chunk combine; hend becomes Hin ----------------
__global__ __launch_bounds__(256) void scan2_kernel(float* __restrict__ hend, const float* __restrict__ Pp){
  const int id = blockIdx.x*256 + threadIdx.x;   // BSZ*DI*DS
  const int s = id & 15, d = (id >> 4) & (DI-1), b = id >> 12;
  float H = 0.0f;
  #pragma unroll 4
  for (int c=0;c<NC;c++){
    const size_t ix = (((size_t)(b*NC + c))*DI + d)*DS + s;
    const float he = hend[ix], p = Pp[ix];
    hend[ix] = H;          // chunk-initial state
    H = fmaf(p, H, he);
  }
}

// ---------------- scan phase 3: re-scan with true init, emit gated y (overwrites dt buffer) ----------------
__global__ __launch_bounds__(256) void scan3_kernel(
    const float* __restrict__ xp, float* __restrict__ dty,
    const float* __restrict__ Bmb, const float* __restrict__ Cmb,
    const float* __restrict__ lamb, const float* __restrict__ zsb,
    const float* __restrict__ Alog, const float* __restrict__ Dv,
    const float* __restrict__ Hin)
{
  const int id = blockIdx.x*256 + threadIdx.x;
  const int d = id & (DI-1);
  const int c = (id >> 8) & (NC-1);
  const int b = id >> 15;
  float A[DS];
  #pragma unroll
  for (int s=0;s<DS;s++) A[s] = fminf(-expf(Alog[d*DS+s]), -1e-4f);
  const float dvp = Dv[d];
  const size_t bL = (size_t)b*SEQL;
  const int t0 = c*TC;
  float h[DS], Bprev[DS];
  load16(Hin + (size_t)id*DS, h);
  #pragma unroll
  for (int s=0;s<DS;s++) Bprev[s]=0.0f;
  float xpm1 = 0.0f;
  int tstart = t0;
  if (t0 > 0){
    load16(Bmb + (bL + t0 - 1)*DS, Bprev);
    xpm1 = xp[(bL + t0 - 1)*DI + d];
  } else {
    const size_t rowE = bL*DI + d;
    const float dtv = dty[rowE];
    const float xpv = xp[rowE];
    float Bcur[DS]; load16(Bmb + bL*DS, Bcur);
    float Ccur[DS]; load16(Cmb + bL*DS, Ccur);
    float y = 0.0f;
    #pragma unroll
    for (int s=0;s<DS;s++){
      h[s] = dtv*(Bcur[s]*xpv);       // h was 0 at t=0
      y = fmaf(h[s], Ccur[s], y);
      Bprev[s] = Bcur[s];
    }
    dty[rowE] = (y + xpv*dvp)*zsb[rowE];
    xpm1 = xpv;
    tstart = 1;
  }
  for (int t=tstart; t<t0+TC; ++t){
    const size_t rowE = (bL + t)*DI + d;
    const float dtv = dty[rowE];
    const float xpv = xp[rowE];
    const float lamv = lamb[bL + t];
    float Bcur[DS]; load16(Bmb + (bL + t)*DS, Bcur);
    float Ccur[DS]; load16(Cmb + (bL + t)*DS, Ccur);
    const float dl = dtv*lamv;
    const float dml = dtv - dl;
    float y = 0.0f;
    #pragma unroll
    for (int s=0;s<DS;s++){
      const float a = __expf(A[s]*dtv);
      const float u = fmaf(dml*a, Bprev[s]*xpm1, dl*(Bcur[s]*xpv));
      h[s] = fmaf(a, h[s], u);
      y = fmaf(h[s], Ccur[s], y);
      Bprev[s] = Bcur[s];
    }
    dty[rowE] = (y + xpv*dvp)*zsb[rowE];
    xpm1 = xpv;
  }
}

// ---------------- out_proj + residual ----------------
__global__ __launch_bounds__(256) void post_kernel(
    const float* __restrict__ yb, const float* __restrict__ Wo,
    float* __restrict__ hb)
{
  __shared__ float yl[NROWS][DI+2];
  const int t = threadIdx.x;
  const size_t R0 = (size_t)blockIdx.x * NROWS;
  #pragma unroll
  for (int r=0;r<NROWS;r++) yl[r][t] = yb[(R0+r)*DI + t];
  __syncthreads();
  const int c = t & (DM-1), g = t >> 7;
  float acc[4] = {0.0f,0.0f,0.0f,0.0f};
  for (int k=0;k<DI;k++){
    const float wv = Wo[(size_t)k*DM + c];
    #pragma unroll
    for (int rr=0;rr<4;rr++) acc[rr] = fmaf(yl[g + rr*2][k], wv, acc[rr]);
  }
  #pragma unroll
  for (int rr=0;rr<4;rr++) hb[(R0 + g + rr*2)*DM + c] += acc[rr];
}

// ---------------- final LN + landmark attention (one block per batch) ----------------
__global__ __launch_bounds__(256) void attn_kernel(
    const float* __restrict__ hb, const float* __restrict__ sk,
    const float* __restrict__ hw,
    const float* __restrict__ fnw, const float* __restrict__ fnb,
    const float* __restrict__ WQ, const float* __restrict__ bQ,
    const float* __restrict__ WK, const float* __restrict__ bK,
    const float* __restrict__ WV, const float* __restrict__ bV,
    const float* __restrict__ WO, const float* __restrict__ bO,
    float* __restrict__ outp)
{
  __shared__ float kv[KLM][DM+1];
  __shared__ float mo[DM];
  __shared__ float Qs[DM];
  __shared__ float qk[NHEAD][DM];
  __shared__ float bterm[NHEAD];
  __shared__ float sc[NHEAD][KLM];
  __shared__ float pbar[NHEAD][DM];
  __shared__ float attno[DM];
  __shared__ int idxl[KLM];
  __shared__ int red_i[4];
  __shared__ float red_f[4];

  const int b = blockIdx.x;
  const int t = threadIdx.x;
  const int lane = t & 63, w = t >> 6;

  // preload hawkes (8/thread); index i = q*256 + t
  const float* hwp = hw + (size_t)b*SEQL;
  unsigned vb[8];
  #pragma unroll
  for (int q=0;q<8;q++) vb[q] = __float_as_uint(hwp[q*256 + t]);

  // 100th-largest via bitwise binary search (values >= 0 so uint order = float order)
  unsigned kth = 0u;
  for (int bit=31; bit>=0; --bit){
    const unsigned cand = kth | (1u << bit);
    int c0 = 0;
    #pragma unroll
    for (int q=0;q<8;q++) c0 += (vb[q] >= cand) ? 1 : 0;
    if (block_isum256(c0, red_i) >= KLM) kth = cand;
  }
  int cg0 = 0;
  #pragma unroll
  for (int q=0;q<8;q++) cg0 += (vb[q] > kth) ? 1 : 0;
  const int cnt_gt = block_isum256(cg0, red_i);
  const int need_eq = KLM - cnt_gt;

  // ordered compaction -> ascending idxl[0..99] (ties: lowest index first)
  int eq_base = 0, sel_base = 0;
  for (int r=0;r<8;r++){
    const bool eq = (vb[r] == kth);
    const bool gt = (vb[r] >  kth);
    const unsigned long long mEq = __ballot(eq);
    __syncthreads();
    if (lane==0) red_i[w] = __popcll(mEq);
    __syncthreads();
    int eqBefore = eq_base + __popcll(mEq & ((1ull<<lane)-1ull));
    for (int j=0;j<w;j++) eqBefore += red_i[j];
    const int eqTot = red_i[0]+red_i[1]+red_i[2]+red_i[3];
    const bool sel = gt || (eq && eqBefore < need_eq);
    const unsigned long long mSel = __ballot(sel);
    __syncthreads();
    if (lane==0) red_i[w] = __popcll(mSel);
    __syncthreads();
    int pos = sel_base + __popcll(mSel & ((1ull<<lane)-1ull));
    for (int j=0;j<w;j++) pos += red_i[j];
    const int selTot = red_i[0]+red_i[1]+red_i[2]+red_i[3];
    if (sel && pos < KLM) idxl[pos] = r*256 + t;
    eq_base += eqTot; sel_base += selTot;
  }
  __syncthreads();

  // mo = LN(h[b, last]) with fn_w/fn_b
  {
    const float* hr = hb + ((size_t)b*SEQL + (SEQL-1))*DM;
    const float hv = (t < DM) ? hr[t] : 0.0f;
    const float ssum = block_sum256(hv, red_f);
    const float mean = ssum*(1.0f/DM);
    const float dv = (t < DM) ? (hv - mean) : 0.0f;
    const float vsum = block_sum256(dv*dv, red_f);
    const float inv = 1.0f/sqrtf(vsum*(1.0f/DM) + 1e-5f);
    if (t < DM) mo[t] = dv*inv*fnw[t] + fnb[t];
  }
  __syncthreads();

  // gather kv
  for (int e=t; e<KLM*DM; e+=256){
    const int j = e >> 7, cc = e & (DM-1);
    kv[j][cc] = sk[((size_t)b*SEQL + idxl[j])*DM + cc];
  }
  __syncthreads();

  // Q = mo@WQ + bQ
  if (t < DM){
    float a = bQ[t];
    #pragma unroll 4
    for (int k=0;k<DM;k++) a = fmaf(mo[k], WQ[(size_t)k*DM + t], a);
    Qs[t] = a;
  }
  __syncthreads();
  // qk[h][m] = sum_{c in head h} WK[m,c]*Q[c]; bterm[h] = sum bK[c]*Q[c]
  for (int e=t; e<NHEAD*DM; e+=256){
    const int hh = e >> 7, m = e & (DM-1);
    const int c0 = hh*DHEAD;
    float a = 0.0f;
    #pragma unroll
    for (int cc=0; cc<DHEAD; cc++) a = fmaf(WK[(size_t)m*DM + c0 + cc], Qs[c0+cc], a);
    qk[hh][m] = a;
  }
  if (t < NHEAD){
    float a = 0.0f;
    for (int cc=0; cc<DHEAD; cc++) a += bK[t*DHEAD+cc]*Qs[t*DHEAD+cc];
    bterm[t] = a;
  }
  __syncthreads();
  // scores
  for (int e=t; e<NHEAD*KLM; e+=256){
    const int hh = e/KLM, j = e - hh*KLM;
    float a = bterm[hh];
    #pragma unroll 4
    for (int m=0;m<DM;m++) a = fmaf(kv[j][m], qk[hh][m], a);
    sc[hh][j] = a*0.17677669529663687f;  // 32^-0.5
  }
  __syncthreads();
  // softmax per head (wave w handles head w)
  {
    const int hh = w;
    const float v0 = (lane < KLM) ? sc[hh][lane] : -3.0e38f;
    const float v1 = (lane+64 < KLM) ? sc[hh][lane+64] : -3.0e38f;
    float mx = fmaxf(v0, v1);
    #pragma unroll
    for (int o2=32;o2>0;o2>>=1) mx = fmaxf(mx, __shfl_xor(mx,o2,64));
    const float e0 = (lane < KLM) ? expf(v0-mx) : 0.0f;
    const float e1 = (lane+64 < KLM) ? expf(v1-mx) : 0.0f;
    float sm = e0+e1;
    #pragma unroll
    for (int o2=32;o2>0;o2>>=1) sm += __shfl_xor(sm,o2,64);
    const float inv2 = 1.0f/sm;
    if (lane < KLM) sc[hh][lane] = e0*inv2;
    if (lane+64 < KLM) sc[hh][lane+64] = e1*inv2;
  }
  __syncthreads();
  // pbar[h][m] = sum_j p[h][j]*kv[j][m]
  for (int e=t; e<NHEAD*DM; e+=256){
    const int hh = e >> 7, m = e & (DM-1);
    float a = 0.0f;
    #pragma unroll 4
    for (int j=0;j<KLM;j++) a = fmaf(sc[hh][j], kv[j][m], a);
    pbar[hh][m] = a;
  }
  __syncthreads();
  // attn out = pbar@WV + bV (head-sliced)
  if (t < DM){
    const int hh = t >> 5;
    float a = bV[t];
    #pragma unroll 4
    for (int m=0;m<DM;m++) a = fmaf(pbar[hh][m], WV[(size_t)m*DM + t], a);
    attno[t] = a;
  }
  __syncthreads();
  if (t < DM){
    float a = bO[t];
    #pragma unroll 4
    for (int c2=0;c2<DM;c2++) a = fmaf(attno[c2], WO[(size_t)c2*DM + t], a);
    outp[(size_t)b*DM + t] = a;
  }
}

extern "C" void kernel_launch(void* const* d_in, const int* in_sizes, int n_in,
                              void* d_out, int out_size, void* d_ws, size_t ws_size,
                              hipStream_t stream)
{
  (void)in_sizes; (void)n_in; (void)out_size; (void)ws_size;
  const float* x    = (const float*)d_in[0];
  const float* hw   = (const float*)d_in[1];
  const float* embW = (const float*)d_in[2];
  const float* embB = (const float*)d_in[3];
  const float* skW  = (const float*)d_in[4];
  const float* skB  = (const float*)d_in[5];
  const float* inW  = (const float*)d_in[6];
  const float* xpW  = (const float*)d_in[7];
  const float* dtW  = (const float*)d_in[8];
  const float* dtB  = (const float*)d_in[9];
  const float* Alog = (const float*)d_in[10];
  const float* Bb   = (const float*)d_in[11];
  const float* Cb   = (const float*)d_in[12];
  const float* Bnw  = (const float*)d_in[13];
  const float* Cnw  = (const float*)d_in[14];
  const float* rf   = (const float*)d_in[15];
  const float* Dpar = (const float*)d_in[16];
  const float* outW = (const float*)d_in[17];
  const float* lnW  = (const float*)d_in[18];
  const float* lnB  = (const float*)d_in[19];
  const float* fnW  = (const float*)d_in[20];
  const float* fnB  = (const float*)d_in[21];
  const float* WQ = (const float*)d_in[22]; const float* bQ = (const float*)d_in[23];
  const float* WK = (const float*)d_in[24]; const float* bK = (const float*)d_in[25];
  const float* WV = (const float*)d_in[26]; const float* bV = (const float*)d_in[27];
  const float* WO = (const float*)d_in[28]; const float* bO = (const float*)d_in[29];

  float* ws = (float*)d_ws;
  size_t off = 0;
  float* hb   = ws + off; off += (size_t)BSZ*SEQL*DM;
  float* sk   = ws + off; off += (size_t)BSZ*SEQL*DM;
  float* xpb  = ws + off; off += (size_t)BSZ*SEQL*DI;
  float* zsb  = ws + off; off += (size_t)BSZ*SEQL*DI;
  float* dtb  = ws + off; off += (size_t)BSZ*SEQL*DI;   // reused as y by scan3
  float* Bmb  = ws + off; off += (size_t)BSZ*SEQL*DS;
  float* Cmb  = ws + off; off += (size_t)BSZ*SEQL*DS;
  float* lamb = ws + off; off += (size_t)BSZ*SEQL;
  float* mdtb = ws + off; off += (size_t)BSZ*SEQL;
  float* hend = ws + off; off += (size_t)BSZ*NC*DI*DS;
  float* Ppb  = ws + off; off += (size_t)BSZ*NC*DI*DS;
  double* angs = (double*)(ws + off);                    // BSZ*SEQL doubles

  embed_kernel<<<BSZ*SEQL, DM, 0, stream>>>(x, hw, embW, embB, skW, skB, hb, sk);

  for (int i=0;i<NL;i++){
    pre_kernel<<<BSZ*SEQL/NROWS, 256, 0, stream>>>(hb,
        inW + (size_t)i*DM*2*DI, xpW + (size_t)i*DI*34,
        dtW + (size_t)i*DI, dtB + (size_t)i*DI,
        Bb + i*DS, Cb + i*DS, Bnw + i*DS, Cnw + i*DS,
        lnW + i*DM, lnB + i*DM,
        xpb, zsb, dtb, Bmb, Cmb, lamb, mdtb);
    cumsum_kernel<<<BSZ, 256, 0, stream>>>(mdtb, angs);
    rot_kernel<<<BSZ*SEQL*8/256, 256, 0, stream>>>(angs, rf + i*8, Bmb, Cmb);
    scan1_kernel<<<BSZ*NC*DI/256, 256, 0, stream>>>(xpb, dtb, Bmb, lamb,
        Alog + (size_t)i*DI*DS, hend, Ppb);
    scan2_kernel<<<BSZ*DI*DS/256, 256, 0, stream>>>(hend, Ppb);
    scan3_kernel<<<BSZ*NC*DI/256, 256, 0, stream>>>(xpb, dtb, Bmb, Cmb, lamb, zsb,
        Alog + (size_t)i*DI*DS, Dpar + (size_t)i*DI, hend);
    post_kernel<<<BSZ*SEQL/NROWS, 256, 0, stream>>>(dtb, outW + (size_t)i*DI*DM, hb);
  }

  attn_kernel<<<BSZ, 256, 0, stream>>>(hb, sk, hw, fnW, fnB,
      WQ, bQ, WK, bK, WV, bV, WO, bO, (float*)d_out);
}